// Round 3
// baseline (1028.176 us; speedup 1.0000x reference)
//
#include <hip/hip_runtime.h>
#include <hip/hip_bf16.h>

// GIN forward: N=10000 nodes, E=80000 edges, per-node feature block [A=2][C=15][D=64]
// x layout: [n][a][c][d] contiguous -> row r = n*30 + a*15 + c, R=300000 rows of 64.
#define N_NODES   10000
#define N_EDGES   80000
#define R_TOTAL   300000
#define ELEMS     19200000   // R_TOTAL*64
#define NODE_F    1920       // 30*64 floats per node

__device__ __forceinline__ float lane_bcast(float v, int k) {
    return __builtin_bit_cast(float, __builtin_amdgcn_readlane(__builtin_bit_cast(int, v), k));
}

// inline BatchNorm coefficient computation (replaces k_bnfin dispatches)
__device__ __forceinline__ void bn_coef(const float* __restrict__ ssum,
                                        const float* __restrict__ ssq,
                                        const float* __restrict__ g,
                                        const float* __restrict__ b, int j,
                                        float& sc, float& sh) {
    const float invM = 1.0f / (float)R_TOTAL;
    float m = ssum[j] * invM;
    float v = ssq[j] * invM - m * m;
    sc = g[j] * rsqrtf(v + 1e-5f);
    sh = b[j] - m * sc;
}

// ---------------- transpose h[a][d][c][n] -> x[n][a][c][d], + pooled0 ----------------
__global__ void k_transpose(const float* __restrict__ h, float* __restrict__ x,
                            float* __restrict__ pooled) {
    __shared__ float tile[64][65];
    __shared__ float pr[4][64];
    int tn = blockIdx.x;              // n-tile 0..156
    int ac = blockIdx.y;              // 0..29
    int a = ac / 15, c = ac % 15;
    int tx = threadIdx.x & 63, ty = threadIdx.x >> 6;
    int n0 = tn * 64;
    const float* hp = h + ((size_t)a * 64 * 15 + c) * 10000;   // + d*150000 + n
    for (int dd = ty; dd < 64; dd += 4) {
        int n = n0 + tx;
        if (n < N_NODES) tile[dd][tx] = hp[(size_t)dd * 150000 + n];
    }
    __syncthreads();
    float ps = 0.f;
    for (int nn = ty; nn < 64; nn += 4) {
        int n = n0 + nn;
        if (n < N_NODES) {
            float val = tile[tx][nn];
            x[((size_t)(n * 30 + ac)) * 64 + tx] = val;
            ps += val;
        }
    }
    pr[ty][tx] = ps;
    __syncthreads();
    if (ty == 0) {
        float s = pr[0][tx] + pr[1][tx] + pr[2][tx] + pr[3][tx];
        atomicAdd(&pooled[ac * 64 + tx], s);
    }
}

// ---------------- CSR build: degree -> scan -> fill ----------------
__global__ void k_deg(const int* __restrict__ dst, int* __restrict__ deg) {
    int e = blockIdx.x * 256 + threadIdx.x;
    if (e < N_EDGES) atomicAdd(&deg[dst[e]], 1);
}

__global__ __launch_bounds__(256) void k_scan(const int* __restrict__ deg,
                                              int* __restrict__ off,
                                              int* __restrict__ cursor) {
    __shared__ int buf[256];
    int t = threadIdx.x;
    int c0 = t * 40;                 // 256*40 = 10240 >= 10000
    int local[40];
    int s = 0;
    for (int i = 0; i < 40; i++) {
        int idx = c0 + i;
        int d = (idx < N_NODES) ? deg[idx] : 0;
        local[i] = d;
        s += d;
    }
    buf[t] = s;
    __syncthreads();
    for (int st = 1; st < 256; st <<= 1) {          // Hillis-Steele inclusive scan
        int v = (t >= st) ? buf[t - st] : 0;
        __syncthreads();
        buf[t] += v;
        __syncthreads();
    }
    int run = buf[t] - s;            // exclusive prefix for this chunk
    for (int i = 0; i < 40; i++) {
        int idx = c0 + i;
        if (idx < N_NODES) {
            off[idx] = run;
            cursor[idx] = run;
            run += local[i];
        }
    }
    if (t == 255) off[N_NODES] = buf[255];
}

__global__ void k_fill(const int* __restrict__ src, const int* __restrict__ dst,
                       int* __restrict__ cursor, int* __restrict__ csr) {
    int e = blockIdx.x * 256 + threadIdx.x;
    if (e < N_EDGES) {
        int p = atomicAdd(&cursor[dst[e]], 1);
        csr[p] = src[e];
    }
}

// ---------------- fused gather + MLP linear0 + stats(t1) ----------------
// one block per dst node: z = (1+eps)*x[n] + sum_{src} x[src]  (regs -> LDS),
// then t1[n] = z @ W0 + b0 per row via readlane-GEMM; channel stats of t1.
__global__ __launch_bounds__(256) void k_aggmlp(const float* __restrict__ x,
                                                float* __restrict__ t,
                                                const int* __restrict__ off,
                                                const int* __restrict__ csr,
                                                const float* __restrict__ W,
                                                const float* __restrict__ bias,
                                                const float* __restrict__ epsp, int l,
                                                float* __restrict__ ssum,
                                                float* __restrict__ ssq) {
    __shared__ float zld[NODE_F];
    __shared__ int eds[64];
    __shared__ float red[2][4][64];
    int n = blockIdx.x;
    int tid = threadIdx.x;
    int j = tid & 63, wid = tid >> 6;

    float w[64];
#pragma unroll
    for (int k = 0; k < 64; k++) w[k] = W[k * 64 + j];
    float bj = bias[j];
    float e1 = 1.0f + epsp[l];

    // ---- gather phase: thread covers float4 idx tid and tid+256 (480 total) ----
    const float4* xs = (const float4*)(x + (size_t)n * NODE_F);
    float4 a0 = xs[tid];
    a0.x *= e1; a0.y *= e1; a0.z *= e1; a0.w *= e1;
    float4 a1 = {0.f, 0.f, 0.f, 0.f};
    bool two = (tid < 480 - 256);
    if (two) {
        a1 = xs[tid + 256];
        a1.x *= e1; a1.y *= e1; a1.z *= e1; a1.w *= e1;
    }
    int e0 = off[n], eE = off[n + 1];
    for (int base = e0; base < eE; base += 64) {
        int cnt = min(64, eE - base);
        if (tid < cnt) eds[tid] = csr[base + tid];
        __syncthreads();
        for (int i = 0; i < cnt; i++) {
            const float4* xr = (const float4*)(x + (size_t)eds[i] * NODE_F);
            float4 v = xr[tid];
            a0.x += v.x; a0.y += v.y; a0.z += v.z; a0.w += v.w;
            if (two) {
                float4 v2 = xr[tid + 256];
                a1.x += v2.x; a1.y += v2.y; a1.z += v2.z; a1.w += v2.w;
            }
        }
        __syncthreads();
    }
    ((float4*)zld)[tid] = a0;
    if (two) ((float4*)zld)[tid + 256] = a1;
    __syncthreads();

    // ---- GEMM phase: wave wid handles rows wid, wid+4, ... ----
    float s0 = 0.f, s1 = 0.f;
    float* trow = t + (size_t)n * NODE_F;
    for (int r = wid; r < 30; r += 4) {
        float zv = zld[r * 64 + j];
        float acc = bj;
#pragma unroll
        for (int k = 0; k < 64; k++) acc = fmaf(lane_bcast(zv, k), w[k], acc);
        trow[r * 64 + j] = acc;
        s0 += acc;
        s1 += acc * acc;
    }
    red[0][wid][j] = s0;
    red[1][wid][j] = s1;
    __syncthreads();
    if (wid == 0) {
        float a = red[0][0][j] + red[0][1][j] + red[0][2][j] + red[0][3][j];
        float b = red[1][0][j] + red[1][1][j] + red[1][2][j] + red[1][3][j];
        atomicAdd(&ssum[j], a);
        atomicAdd(&ssq[j], b);
    }
}

// ---------------- passB: t = relu(bn0(t)) @ W1 + b1 ; stats(t3). bn0 inline ----------------
__global__ __launch_bounds__(256) void k_passB(float* __restrict__ t,
                                               const float* __restrict__ W,
                                               const float* __restrict__ bias,
                                               const float* __restrict__ ssum0,
                                               const float* __restrict__ ssq0,
                                               const float* __restrict__ g0,
                                               const float* __restrict__ be0,
                                               float* __restrict__ ssum, float* __restrict__ ssq) {
    int j = threadIdx.x & 63;
    int wid = threadIdx.x >> 6;
    float w[64];
#pragma unroll
    for (int k = 0; k < 64; k++) w[k] = W[k * 64 + j];
    float bj = bias[j];
    float sc, sh;
    bn_coef(ssum0, ssq0, g0, be0, j, sc, sh);
    float s0 = 0.f, s1 = 0.f;
    const int nGroups = R_TOTAL / 4;
    for (int g = blockIdx.x; g < nGroups; g += gridDim.x) {
        size_t base = ((size_t)g * 4 + wid) * 64;
        float zv = fmaxf(fmaf(t[base + j], sc, sh), 0.f);
        float acc = bj;
#pragma unroll
        for (int k = 0; k < 64; k++) acc = fmaf(lane_bcast(zv, k), w[k], acc);
        t[base + j] = acc;
        s0 += acc;
        s1 += acc * acc;
    }
    __shared__ float red[2][4][64];
    red[0][wid][j] = s0;
    red[1][wid][j] = s1;
    __syncthreads();
    if (wid == 0) {
        float a = red[0][0][j] + red[0][1][j] + red[0][2][j] + red[0][3][j];
        float b = red[1][0][j] + red[1][1][j] + red[1][2][j] + red[1][3][j];
        atomicAdd(&ssum[j], a);
        atomicAdd(&ssq[j], b);
    }
}

// ---------------- statsC: stats of u = relu(bn_a(t3)), read-only ----------------
__global__ __launch_bounds__(256) void k_statsC(const float* __restrict__ t,
                                                const float* __restrict__ ssum1,
                                                const float* __restrict__ ssq1,
                                                const float* __restrict__ ga,
                                                const float* __restrict__ ba,
                                                float* __restrict__ ssum2,
                                                float* __restrict__ ssq2) {
    __shared__ float shs0[64], shs1[64];
    int tid = threadIdx.x;
    if (tid < 64) { shs0[tid] = 0.f; shs1[tid] = 0.f; }
    __syncthreads();
    int q = tid & 15;
    float sc[4], sh[4];
#pragma unroll
    for (int u = 0; u < 4; u++) bn_coef(ssum1, ssq1, ga, ba, q * 4 + u, sc[u], sh[u]);
    float s0[4] = {0, 0, 0, 0}, s1[4] = {0, 0, 0, 0};
    const float4* t4 = (const float4*)t;
    const int total4 = ELEMS / 4;
    int stride = gridDim.x * 256;
    for (int i = blockIdx.x * 256 + tid; i < total4; i += stride) {
        float4 v = t4[i];
        float e;
        e = fmaxf(fmaf(v.x, sc[0], sh[0]), 0.f); s0[0] += e; s1[0] += e * e;
        e = fmaxf(fmaf(v.y, sc[1], sh[1]), 0.f); s0[1] += e; s1[1] += e * e;
        e = fmaxf(fmaf(v.z, sc[2], sh[2]), 0.f); s0[2] += e; s1[2] += e * e;
        e = fmaxf(fmaf(v.w, sc[3], sh[3]), 0.f); s0[3] += e; s1[3] += e * e;
    }
#pragma unroll
    for (int u = 0; u < 4; u++) {
        atomicAdd(&shs0[q * 4 + u], s0[u]);
        atomicAdd(&shs1[q * 4 + u], s1[u]);
    }
    __syncthreads();
    if (tid < 64) {
        atomicAdd(&ssum2[tid], shs0[tid]);
        atomicAdd(&ssq2[tid], shs1[tid]);
    }
}

// ---------------- passD: x = relu(bn_o(relu(bn_a(t3)))) in place + pooled ----------------
__global__ __launch_bounds__(256) void k_passD(float* __restrict__ t,
                                               const float* __restrict__ ssum1,
                                               const float* __restrict__ ssq1,
                                               const float* __restrict__ ga,
                                               const float* __restrict__ ba,
                                               const float* __restrict__ ssum2,
                                               const float* __restrict__ ssq2,
                                               const float* __restrict__ go,
                                               const float* __restrict__ bo,
                                               float* __restrict__ pooled) {
    int tid = threadIdx.x;
    int q = tid & 15;                 // same channel set for tid and tid+256
    float sc1[4], sh1[4], sc2[4], sh2[4];
#pragma unroll
    for (int u = 0; u < 4; u++) {
        bn_coef(ssum1, ssq1, ga, ba, q * 4 + u, sc1[u], sh1[u]);
        bn_coef(ssum2, ssq2, go, bo, q * 4 + u, sc2[u], sh2[u]);
    }
    float4 P0 = {0, 0, 0, 0}, P1 = {0, 0, 0, 0};
    bool two = (tid < 480 - 256);
    for (int n = blockIdx.x; n < N_NODES; n += gridDim.x) {
        float4* tb = (float4*)(t + (size_t)n * NODE_F);
        float4 v = tb[tid];
        v.x = fmaxf(fmaf(fmaxf(fmaf(v.x, sc1[0], sh1[0]), 0.f), sc2[0], sh2[0]), 0.f);
        v.y = fmaxf(fmaf(fmaxf(fmaf(v.y, sc1[1], sh1[1]), 0.f), sc2[1], sh2[1]), 0.f);
        v.z = fmaxf(fmaf(fmaxf(fmaf(v.z, sc1[2], sh1[2]), 0.f), sc2[2], sh2[2]), 0.f);
        v.w = fmaxf(fmaf(fmaxf(fmaf(v.w, sc1[3], sh1[3]), 0.f), sc2[3], sh2[3]), 0.f);
        tb[tid] = v;
        P0.x += v.x; P0.y += v.y; P0.z += v.z; P0.w += v.w;
        if (two) {
            float4 v2 = tb[tid + 256];
            v2.x = fmaxf(fmaf(fmaxf(fmaf(v2.x, sc1[0], sh1[0]), 0.f), sc2[0], sh2[0]), 0.f);
            v2.y = fmaxf(fmaf(fmaxf(fmaf(v2.y, sc1[1], sh1[1]), 0.f), sc2[1], sh2[1]), 0.f);
            v2.z = fmaxf(fmaf(fmaxf(fmaf(v2.z, sc1[2], sh1[2]), 0.f), sc2[2], sh2[2]), 0.f);
            v2.w = fmaxf(fmaf(fmaxf(fmaf(v2.w, sc1[3], sh1[3]), 0.f), sc2[3], sh2[3]), 0.f);
            tb[tid + 256] = v2;
            P1.x += v2.x; P1.y += v2.y; P1.z += v2.z; P1.w += v2.w;
        }
    }
    float* pb0 = pooled + tid * 4;
    atomicAdd(pb0 + 0, P0.x); atomicAdd(pb0 + 1, P0.y);
    atomicAdd(pb0 + 2, P0.z); atomicAdd(pb0 + 3, P0.w);
    if (two) {
        float* pb1 = pooled + (tid + 256) * 4;
        atomicAdd(pb1 + 0, P1.x); atomicAdd(pb1 + 1, P1.y);
        atomicAdd(pb1 + 2, P1.z); atomicAdd(pb1 + 3, P1.w);
    }
}

// ---------------- final readout: score + fc -> out[2] ----------------
__global__ void k_final(const float* __restrict__ pooled,   // [3][1920]
                        const float* __restrict__ Wp,       // [3][64][10]
                        const float* __restrict__ bp,       // [3][10]
                        const float* __restrict__ Wfc,      // [15][10]
                        const float* __restrict__ bfc, float* __restrict__ out) {
    __shared__ float oa[2];
    int t = threadIdx.x;
    if (t < 2) oa[t] = 0.f;
    __syncthreads();
    if (t < 300) {
        int a = t / 150, rem = t % 150, c = rem / 10, hh = rem % 10;
        int ac = a * 15 + c;
        float sc_sum = 0.f;
        for (int i = 0; i < 3; i++) {
            float s = bp[i * 10 + hh];
            const float* pp = pooled + i * NODE_F + ac * 64;
            const float* wp = Wp + i * 640 + hh;
            for (int d = 0; d < 64; d++) s += pp[d] * wp[d * 10];
            sc_sum += s;
        }
        atomicAdd(&oa[a], sc_sum * Wfc[c * 10 + hh]);
    }
    __syncthreads();
    if (t < 2) out[t] = oa[t] + bfc[0];
}

extern "C" void kernel_launch(void* const* d_in, const int* in_sizes, int n_in,
                              void* d_out, int out_size, void* d_ws, size_t ws_size,
                              hipStream_t stream) {
    const float* h   = (const float*)d_in[0];
    const float* eps = (const float*)d_in[1];
    const float* W0  = (const float*)d_in[2];
    const float* b0  = (const float*)d_in[3];
    const float* g0  = (const float*)d_in[4];
    const float* be0 = (const float*)d_in[5];
    const float* W1  = (const float*)d_in[6];
    const float* b1  = (const float*)d_in[7];
    const float* ga  = (const float*)d_in[8];
    const float* ba  = (const float*)d_in[9];
    const float* go  = (const float*)d_in[10];
    const float* bo  = (const float*)d_in[11];
    const float* Wp  = (const float*)d_in[12];
    const float* bp  = (const float*)d_in[13];
    const float* Wfc = (const float*)d_in[14];
    const float* bfc = (const float*)d_in[15];
    const int*   src = (const int*)d_in[16];
    const int*   dst = (const int*)d_in[17];
    float* out = (float*)d_out;

    float* bufA = (float*)d_ws;
    float* bufB = bufA + ELEMS;
    float* small = bufB + ELEMS;
    float* bn = small;                   // 6 BN instances x [sum64|sq64] (+pad to 256)
    float* pooled = small + 6 * 256;     // [3][1920]
    int* ideg   = (int*)(pooled + 3 * NODE_F);   // [10000]
    int* ioff   = ideg + N_NODES;                // [10001]
    int* icur   = ioff + N_NODES + 1;            // [10000]
    int* icsr   = icur + N_NODES;                // [80000]

    // zero: bn stats + pooled + deg histogram (one contiguous region)
    hipMemsetAsync(small, 0,
                   (6 * 256 + 3 * NODE_F) * sizeof(float) + N_NODES * sizeof(int), stream);

    // CSR build (once; reused by both layers)
    k_deg<<<(N_EDGES + 255) / 256, 256, 0, stream>>>(dst, ideg);
    k_scan<<<1, 256, 0, stream>>>(ideg, ioff, icur);
    k_fill<<<(N_EDGES + 255) / 256, 256, 0, stream>>>(src, dst, icur, icsr);

    k_transpose<<<dim3(157, 30), 256, 0, stream>>>(h, bufA, pooled);

    float* cur = bufA;
    float* oth = bufB;
    for (int l = 0; l < 2; l++) {
        float* s0s = bn + l * 3 * 256;
        float* s1s = s0s + 256;
        float* s2s = s1s + 256;
        k_aggmlp<<<N_NODES, 256, 0, stream>>>(cur, oth, ioff, icsr,
                                              W0 + l * 4096, b0 + l * 64, eps, l,
                                              s0s, s0s + 64);
        k_passB<<<2048, 256, 0, stream>>>(oth, W1 + l * 4096, b1 + l * 64,
                                          s0s, s0s + 64, g0 + l * 64, be0 + l * 64,
                                          s1s, s1s + 64);
        k_statsC<<<1024, 256, 0, stream>>>(oth, s1s, s1s + 64, ga + l * 64, ba + l * 64,
                                           s2s, s2s + 64);
        k_passD<<<640, 256, 0, stream>>>(oth, s1s, s1s + 64, ga + l * 64, ba + l * 64,
                                         s2s, s2s + 64, go + l * 64, bo + l * 64,
                                         pooled + (l + 1) * NODE_F);
        float* tmp = cur; cur = oth; oth = tmp;
    }
    k_final<<<1, 320, 0, stream>>>(pooled, Wp, bp, Wfc, bfc, out);
}

// Round 4
// 880.192 us; speedup vs baseline: 1.1681x; 1.1681x over previous
//
#include <hip/hip_runtime.h>
#include <hip/hip_bf16.h>

// GIN forward: N=10000 nodes, E=80000 edges, per-node feature block [A=2][C=15][D=64]
// x layout: [n][a][c][d] contiguous -> row r = n*30 + a*15 + c, R=300000 rows of 64.
#define N_NODES   10000
#define N_EDGES   80000
#define R_TOTAL   300000
#define ELEMS     19200000   // R_TOTAL*64
#define NODE_F    1920       // 30*64 floats per node

__device__ __forceinline__ float lane_bcast(float v, int k) {
    return __builtin_bit_cast(float, __builtin_amdgcn_readlane(__builtin_bit_cast(int, v), k));
}

// inline BatchNorm coefficient computation
__device__ __forceinline__ void bn_coef(const float* __restrict__ ssum,
                                        const float* __restrict__ ssq,
                                        const float* __restrict__ g,
                                        const float* __restrict__ b, int j,
                                        float& sc, float& sh) {
    const float invM = 1.0f / (float)R_TOTAL;
    float m = ssum[j] * invM;
    float v = ssq[j] * invM - m * m;
    sc = g[j] * rsqrtf(v + 1e-5f);
    sh = b[j] - m * sc;
}

// ---------------- transpose h[a][d][c][n] -> x[n][a][c][d], + pooled0 ----------------
__global__ void k_transpose(const float* __restrict__ h, float* __restrict__ x,
                            float* __restrict__ pooled) {
    __shared__ float tile[64][65];
    __shared__ float pr[4][64];
    int tn = blockIdx.x;              // n-tile 0..156
    int ac = blockIdx.y;              // 0..29
    int a = ac / 15, c = ac % 15;
    int tx = threadIdx.x & 63, ty = threadIdx.x >> 6;
    int n0 = tn * 64;
    const float* hp = h + ((size_t)a * 64 * 15 + c) * 10000;   // + d*150000 + n
    for (int dd = ty; dd < 64; dd += 4) {
        int n = n0 + tx;
        if (n < N_NODES) tile[dd][tx] = hp[(size_t)dd * 150000 + n];
    }
    __syncthreads();
    float ps = 0.f;
    for (int nn = ty; nn < 64; nn += 4) {
        int n = n0 + nn;
        if (n < N_NODES) {
            float val = tile[tx][nn];
            x[((size_t)(n * 30 + ac)) * 64 + tx] = val;
            ps += val;
        }
    }
    pr[ty][tx] = ps;
    __syncthreads();
    if (ty == 0) {
        float s = pr[0][tx] + pr[1][tx] + pr[2][tx] + pr[3][tx];
        atomicAdd(&pooled[ac * 64 + tx], s);
    }
}

// ---------------- CSR build: degree -> scan -> fill ----------------
__global__ void k_deg(const int* __restrict__ dst, int* __restrict__ deg) {
    int e = blockIdx.x * 256 + threadIdx.x;
    if (e < N_EDGES) atomicAdd(&deg[dst[e]], 1);
}

__global__ __launch_bounds__(256) void k_scan(const int* __restrict__ deg,
                                              int* __restrict__ off,
                                              int* __restrict__ cursor) {
    __shared__ int buf[256];
    int t = threadIdx.x;
    int c0 = t * 40;                 // 256*40 = 10240 >= 10000
    int local[40];
    int s = 0;
    for (int i = 0; i < 40; i++) {
        int idx = c0 + i;
        int d = (idx < N_NODES) ? deg[idx] : 0;
        local[i] = d;
        s += d;
    }
    buf[t] = s;
    __syncthreads();
    for (int st = 1; st < 256; st <<= 1) {          // Hillis-Steele inclusive scan
        int v = (t >= st) ? buf[t - st] : 0;
        __syncthreads();
        buf[t] += v;
        __syncthreads();
    }
    int run = buf[t] - s;            // exclusive prefix for this chunk
    for (int i = 0; i < 40; i++) {
        int idx = c0 + i;
        if (idx < N_NODES) {
            off[idx] = run;
            cursor[idx] = run;
            run += local[i];
        }
    }
    if (t == 255) off[N_NODES] = buf[255];
}

__global__ void k_fill(const int* __restrict__ src, const int* __restrict__ dst,
                       int* __restrict__ cursor, int* __restrict__ csr) {
    int e = blockIdx.x * 256 + threadIdx.x;
    if (e < N_EDGES) {
        int p = atomicAdd(&cursor[dst[e]], 1);
        csr[p] = src[e];
    }
}

// ---------------- gather aggregation: agg[n] = sum_{e in in(n)} x[csr_src[e]] ----------------
__global__ __launch_bounds__(256) void k_gather(const float* __restrict__ x,
                                                float* __restrict__ agg,
                                                const int* __restrict__ off,
                                                const int* __restrict__ csr) {
    __shared__ int eds[256];
    int n = blockIdx.x;
    int t = threadIdx.x;
    int e0 = off[n], e1 = off[n + 1];
    float4 acc0 = {0.f, 0.f, 0.f, 0.f};
    float4 acc1 = {0.f, 0.f, 0.f, 0.f};
    for (int base = e0; base < e1; base += 256) {
        int cnt = min(256, e1 - base);
        __syncthreads();
        if (t < cnt) eds[t] = csr[base + t];
        __syncthreads();
        for (int i = 0; i < cnt; i++) {
            const float4* xr = (const float4*)(x + (size_t)eds[i] * NODE_F);
            float4 v = xr[t];
            acc0.x += v.x; acc0.y += v.y; acc0.z += v.z; acc0.w += v.w;
            if (t + 256 < 480) {
                float4 v2 = xr[t + 256];
                acc1.x += v2.x; acc1.y += v2.y; acc1.z += v2.z; acc1.w += v2.w;
            }
        }
    }
    float4* ab = (float4*)(agg + (size_t)n * NODE_F);
    ab[t] = acc0;
    if (t + 256 < 480) ab[t + 256] = acc1;
}

// ---------------- passA: t = ((1+eps)*x + agg) @ W + b ; channel stats of t ----------------
__global__ __launch_bounds__(256) void k_passA(const float* __restrict__ x,
                                               float* __restrict__ t,  // agg in, t1 out (in-place)
                                               const float* __restrict__ W,
                                               const float* __restrict__ bias,
                                               const float* __restrict__ epsp, int l,
                                               float* __restrict__ ssum, float* __restrict__ ssq) {
    int j = threadIdx.x & 63;
    int wid = threadIdx.x >> 6;
    float w[64];
#pragma unroll
    for (int k = 0; k < 64; k++) w[k] = W[k * 64 + j];
    float bj = bias[j];
    float e1 = 1.0f + epsp[l];
    float s0 = 0.f, s1 = 0.f;
    const int nGroups = R_TOTAL / 4;
    for (int g = blockIdx.x; g < nGroups; g += gridDim.x) {
        size_t base = ((size_t)g * 4 + wid) * 64;
        float zv = fmaf(e1, x[base + j], t[base + j]);
        float acc = bj;
#pragma unroll
        for (int k = 0; k < 64; k++) acc = fmaf(lane_bcast(zv, k), w[k], acc);
        t[base + j] = acc;
        s0 += acc;
        s1 += acc * acc;
    }
    __shared__ float red[2][4][64];
    red[0][wid][j] = s0;
    red[1][wid][j] = s1;
    __syncthreads();
    if (wid == 0) {
        float a = red[0][0][j] + red[0][1][j] + red[0][2][j] + red[0][3][j];
        float b = red[1][0][j] + red[1][1][j] + red[1][2][j] + red[1][3][j];
        atomicAdd(&ssum[j], a);
        atomicAdd(&ssq[j], b);
    }
}

// ---------------- passB: t = relu(bn0(t)) @ W1 + b1 ; stats(t3). bn0 inline ----------------
__global__ __launch_bounds__(256) void k_passB(float* __restrict__ t,
                                               const float* __restrict__ W,
                                               const float* __restrict__ bias,
                                               const float* __restrict__ ssum0,
                                               const float* __restrict__ ssq0,
                                               const float* __restrict__ g0,
                                               const float* __restrict__ be0,
                                               float* __restrict__ ssum, float* __restrict__ ssq) {
    int j = threadIdx.x & 63;
    int wid = threadIdx.x >> 6;
    float w[64];
#pragma unroll
    for (int k = 0; k < 64; k++) w[k] = W[k * 64 + j];
    float bj = bias[j];
    float sc, sh;
    bn_coef(ssum0, ssq0, g0, be0, j, sc, sh);
    float s0 = 0.f, s1 = 0.f;
    const int nGroups = R_TOTAL / 4;
    for (int g = blockIdx.x; g < nGroups; g += gridDim.x) {
        size_t base = ((size_t)g * 4 + wid) * 64;
        float zv = fmaxf(fmaf(t[base + j], sc, sh), 0.f);
        float acc = bj;
#pragma unroll
        for (int k = 0; k < 64; k++) acc = fmaf(lane_bcast(zv, k), w[k], acc);
        t[base + j] = acc;
        s0 += acc;
        s1 += acc * acc;
    }
    __shared__ float red[2][4][64];
    red[0][wid][j] = s0;
    red[1][wid][j] = s1;
    __syncthreads();
    if (wid == 0) {
        float a = red[0][0][j] + red[0][1][j] + red[0][2][j] + red[0][3][j];
        float b = red[1][0][j] + red[1][1][j] + red[1][2][j] + red[1][3][j];
        atomicAdd(&ssum[j], a);
        atomicAdd(&ssq[j], b);
    }
}

// ---------------- statsC: stats of u = relu(bn_a(t3)), read-only ----------------
__global__ __launch_bounds__(256) void k_statsC(const float* __restrict__ t,
                                                const float* __restrict__ ssum1,
                                                const float* __restrict__ ssq1,
                                                const float* __restrict__ ga,
                                                const float* __restrict__ ba,
                                                float* __restrict__ ssum2,
                                                float* __restrict__ ssq2) {
    __shared__ float shs0[64], shs1[64];
    int tid = threadIdx.x;
    if (tid < 64) { shs0[tid] = 0.f; shs1[tid] = 0.f; }
    __syncthreads();
    int q = tid & 15;
    float sc[4], sh[4];
#pragma unroll
    for (int u = 0; u < 4; u++) bn_coef(ssum1, ssq1, ga, ba, q * 4 + u, sc[u], sh[u]);
    float s0[4] = {0, 0, 0, 0}, s1[4] = {0, 0, 0, 0};
    const float4* t4 = (const float4*)t;
    const int total4 = ELEMS / 4;
    int stride = gridDim.x * 256;
    for (int i = blockIdx.x * 256 + tid; i < total4; i += stride) {
        float4 v = t4[i];
        float e;
        e = fmaxf(fmaf(v.x, sc[0], sh[0]), 0.f); s0[0] += e; s1[0] += e * e;
        e = fmaxf(fmaf(v.y, sc[1], sh[1]), 0.f); s0[1] += e; s1[1] += e * e;
        e = fmaxf(fmaf(v.z, sc[2], sh[2]), 0.f); s0[2] += e; s1[2] += e * e;
        e = fmaxf(fmaf(v.w, sc[3], sh[3]), 0.f); s0[3] += e; s1[3] += e * e;
    }
#pragma unroll
    for (int u = 0; u < 4; u++) {
        atomicAdd(&shs0[q * 4 + u], s0[u]);
        atomicAdd(&shs1[q * 4 + u], s1[u]);
    }
    __syncthreads();
    if (tid < 64) {
        atomicAdd(&ssum2[tid], shs0[tid]);
        atomicAdd(&ssq2[tid], shs1[tid]);
    }
}

// ---------------- passD: x = relu(bn_o(relu(bn_a(t3)))) in place + pooled ----------------
__global__ __launch_bounds__(256) void k_passD(float* __restrict__ t,
                                               const float* __restrict__ ssum1,
                                               const float* __restrict__ ssq1,
                                               const float* __restrict__ ga,
                                               const float* __restrict__ ba,
                                               const float* __restrict__ ssum2,
                                               const float* __restrict__ ssq2,
                                               const float* __restrict__ go,
                                               const float* __restrict__ bo,
                                               float* __restrict__ pooled) {
    int tid = threadIdx.x;
    int q = tid & 15;                 // same channel set for tid and tid+256
    float sc1[4], sh1[4], sc2[4], sh2[4];
#pragma unroll
    for (int u = 0; u < 4; u++) {
        bn_coef(ssum1, ssq1, ga, ba, q * 4 + u, sc1[u], sh1[u]);
        bn_coef(ssum2, ssq2, go, bo, q * 4 + u, sc2[u], sh2[u]);
    }
    float4 P0 = {0, 0, 0, 0}, P1 = {0, 0, 0, 0};
    bool two = (tid < 480 - 256);
    for (int n = blockIdx.x; n < N_NODES; n += gridDim.x) {
        float4* tb = (float4*)(t + (size_t)n * NODE_F);
        float4 v = tb[tid];
        v.x = fmaxf(fmaf(fmaxf(fmaf(v.x, sc1[0], sh1[0]), 0.f), sc2[0], sh2[0]), 0.f);
        v.y = fmaxf(fmaf(fmaxf(fmaf(v.y, sc1[1], sh1[1]), 0.f), sc2[1], sh2[1]), 0.f);
        v.z = fmaxf(fmaf(fmaxf(fmaf(v.z, sc1[2], sh1[2]), 0.f), sc2[2], sh2[2]), 0.f);
        v.w = fmaxf(fmaf(fmaxf(fmaf(v.w, sc1[3], sh1[3]), 0.f), sc2[3], sh2[3]), 0.f);
        tb[tid] = v;
        P0.x += v.x; P0.y += v.y; P0.z += v.z; P0.w += v.w;
        if (two) {
            float4 v2 = tb[tid + 256];
            v2.x = fmaxf(fmaf(fmaxf(fmaf(v2.x, sc1[0], sh1[0]), 0.f), sc2[0], sh2[0]), 0.f);
            v2.y = fmaxf(fmaf(fmaxf(fmaf(v2.y, sc1[1], sh1[1]), 0.f), sc2[1], sh2[1]), 0.f);
            v2.z = fmaxf(fmaf(fmaxf(fmaf(v2.z, sc1[2], sh1[2]), 0.f), sc2[2], sh2[2]), 0.f);
            v2.w = fmaxf(fmaf(fmaxf(fmaf(v2.w, sc1[3], sh1[3]), 0.f), sc2[3], sh2[3]), 0.f);
            tb[tid + 256] = v2;
            P1.x += v2.x; P1.y += v2.y; P1.z += v2.z; P1.w += v2.w;
        }
    }
    float* pb0 = pooled + tid * 4;
    atomicAdd(pb0 + 0, P0.x); atomicAdd(pb0 + 1, P0.y);
    atomicAdd(pb0 + 2, P0.z); atomicAdd(pb0 + 3, P0.w);
    if (two) {
        float* pb1 = pooled + (tid + 256) * 4;
        atomicAdd(pb1 + 0, P1.x); atomicAdd(pb1 + 1, P1.y);
        atomicAdd(pb1 + 2, P1.z); atomicAdd(pb1 + 3, P1.w);
    }
}

// ---------------- final readout: score + fc -> out[2] ----------------
__global__ void k_final(const float* __restrict__ pooled,   // [3][1920]
                        const float* __restrict__ Wp,       // [3][64][10]
                        const float* __restrict__ bp,       // [3][10]
                        const float* __restrict__ Wfc,      // [15][10]
                        const float* __restrict__ bfc, float* __restrict__ out) {
    __shared__ float oa[2];
    int t = threadIdx.x;
    if (t < 2) oa[t] = 0.f;
    __syncthreads();
    if (t < 300) {
        int a = t / 150, rem = t % 150, c = rem / 10, hh = rem % 10;
        int ac = a * 15 + c;
        float sc_sum = 0.f;
        for (int i = 0; i < 3; i++) {
            float s = bp[i * 10 + hh];
            const float* pp = pooled + i * NODE_F + ac * 64;
            const float* wp = Wp + i * 640 + hh;
            for (int d = 0; d < 64; d++) s += pp[d] * wp[d * 10];
            sc_sum += s;
        }
        atomicAdd(&oa[a], sc_sum * Wfc[c * 10 + hh]);
    }
    __syncthreads();
    if (t < 2) out[t] = oa[t] + bfc[0];
}

extern "C" void kernel_launch(void* const* d_in, const int* in_sizes, int n_in,
                              void* d_out, int out_size, void* d_ws, size_t ws_size,
                              hipStream_t stream) {
    const float* h   = (const float*)d_in[0];
    const float* eps = (const float*)d_in[1];
    const float* W0  = (const float*)d_in[2];
    const float* b0  = (const float*)d_in[3];
    const float* g0  = (const float*)d_in[4];
    const float* be0 = (const float*)d_in[5];
    const float* W1  = (const float*)d_in[6];
    const float* b1  = (const float*)d_in[7];
    const float* ga  = (const float*)d_in[8];
    const float* ba  = (const float*)d_in[9];
    const float* go  = (const float*)d_in[10];
    const float* bo  = (const float*)d_in[11];
    const float* Wp  = (const float*)d_in[12];
    const float* bp  = (const float*)d_in[13];
    const float* Wfc = (const float*)d_in[14];
    const float* bfc = (const float*)d_in[15];
    const int*   src = (const int*)d_in[16];
    const int*   dst = (const int*)d_in[17];
    float* out = (float*)d_out;

    float* bufA = (float*)d_ws;
    float* bufB = bufA + ELEMS;
    float* small = bufB + ELEMS;
    float* bn = small;                   // 6 BN instances x [sum64|sq64] (+pad to 256)
    float* pooled = small + 6 * 256;     // [3][1920]
    int* ideg   = (int*)(pooled + 3 * NODE_F);   // [10000]
    int* ioff   = ideg + N_NODES;                // [10001]
    int* icur   = ioff + N_NODES + 1;            // [10000]
    int* icsr   = icur + N_NODES;                // [80000]

    // zero: bn stats + pooled + deg histogram (one contiguous region)
    hipMemsetAsync(small, 0,
                   (6 * 256 + 3 * NODE_F) * sizeof(float) + N_NODES * sizeof(int), stream);

    // CSR build (once; reused by both layers)
    k_deg<<<(N_EDGES + 255) / 256, 256, 0, stream>>>(dst, ideg);
    k_scan<<<1, 256, 0, stream>>>(ideg, ioff, icur);
    k_fill<<<(N_EDGES + 255) / 256, 256, 0, stream>>>(src, dst, icur, icsr);

    k_transpose<<<dim3(157, 30), 256, 0, stream>>>(h, bufA, pooled);

    float* cur = bufA;
    float* oth = bufB;
    for (int l = 0; l < 2; l++) {
        float* s0s = bn + l * 3 * 256;
        float* s1s = s0s + 256;
        float* s2s = s1s + 256;
        k_gather<<<N_NODES, 256, 0, stream>>>(cur, oth, ioff, icsr);
        k_passA<<<2048, 256, 0, stream>>>(cur, oth, W0 + l * 4096, b0 + l * 64, eps, l,
                                          s0s, s0s + 64);
        k_passB<<<2048, 256, 0, stream>>>(oth, W1 + l * 4096, b1 + l * 64,
                                          s0s, s0s + 64, g0 + l * 64, be0 + l * 64,
                                          s1s, s1s + 64);
        k_statsC<<<1024, 256, 0, stream>>>(oth, s1s, s1s + 64, ga + l * 64, ba + l * 64,
                                           s2s, s2s + 64);
        k_passD<<<640, 256, 0, stream>>>(oth, s1s, s1s + 64, ga + l * 64, ba + l * 64,
                                         s2s, s2s + 64, go + l * 64, bo + l * 64,
                                         pooled + (l + 1) * NODE_F);
        float* tmp = cur; cur = oth; oth = tmp;
    }
    k_final<<<1, 320, 0, stream>>>(pooled, Wp, bp, Wfc, bfc, out);
}

// Round 5
// 790.047 us; speedup vs baseline: 1.3014x; 1.1141x over previous
//
#include <hip/hip_runtime.h>
#include <hip/hip_bf16.h>

// GIN forward: N=10000 nodes, E=80000 edges, per-node feature block [A=2][C=15][D=64]
// x layout: [n][a][c][d] contiguous -> row r = n*30 + a*15 + c, R=300000 rows of 64.
#define N_NODES   10000
#define N_EDGES   80000
#define R_TOTAL   300000
#define ELEMS     19200000   // R_TOTAL*64
#define NODE_F    1920       // 30*64 floats per node
#define N_TILES   18750      // R_TOTAL/16

typedef __attribute__((ext_vector_type(8))) short short8;   // 8 bf16 (4 VGPRs)
typedef __attribute__((ext_vector_type(4))) float f32x4;

__device__ __forceinline__ unsigned short f2bf(float f) {
    unsigned u = __builtin_bit_cast(unsigned, f);
    unsigned r = u + 0x7fff + ((u >> 16) & 1);   // RNE
    return (unsigned short)(r >> 16);
}

// inline BatchNorm coefficient computation
__device__ __forceinline__ void bn_coef(const float* __restrict__ ssum,
                                        const float* __restrict__ ssq,
                                        const float* __restrict__ g,
                                        const float* __restrict__ b, int j,
                                        float& sc, float& sh) {
    const float invM = 1.0f / (float)R_TOTAL;
    float m = ssum[j] * invM;
    float v = ssq[j] * invM - m * m;
    sc = g[j] * rsqrtf(v + 1e-5f);
    sh = b[j] - m * sc;
}

// ---------------- transpose h[a][d][c][n] -> x[n][a][c][d], + pooled0 ----------------
__global__ void k_transpose(const float* __restrict__ h, float* __restrict__ x,
                            float* __restrict__ pooled) {
    __shared__ float tile[64][65];
    __shared__ float pr[4][64];
    int tn = blockIdx.x;              // n-tile 0..156
    int ac = blockIdx.y;              // 0..29
    int a = ac / 15, c = ac % 15;
    int tx = threadIdx.x & 63, ty = threadIdx.x >> 6;
    int n0 = tn * 64;
    const float* hp = h + ((size_t)a * 64 * 15 + c) * 10000;   // + d*150000 + n
    for (int dd = ty; dd < 64; dd += 4) {
        int n = n0 + tx;
        if (n < N_NODES) tile[dd][tx] = hp[(size_t)dd * 150000 + n];
    }
    __syncthreads();
    float ps = 0.f;
    for (int nn = ty; nn < 64; nn += 4) {
        int n = n0 + nn;
        if (n < N_NODES) {
            float val = tile[tx][nn];
            x[((size_t)(n * 30 + ac)) * 64 + tx] = val;
            ps += val;
        }
    }
    pr[ty][tx] = ps;
    __syncthreads();
    if (ty == 0) {
        float s = pr[0][tx] + pr[1][tx] + pr[2][tx] + pr[3][tx];
        atomicAdd(&pooled[ac * 64 + tx], s);
    }
}

// ---------------- CSR build: degree -> scan -> fill ----------------
__global__ void k_deg(const int* __restrict__ dst, int* __restrict__ deg) {
    int e = blockIdx.x * 256 + threadIdx.x;
    if (e < N_EDGES) atomicAdd(&deg[dst[e]], 1);
}

__global__ __launch_bounds__(256) void k_scan(const int* __restrict__ deg,
                                              int* __restrict__ off,
                                              int* __restrict__ cursor) {
    __shared__ int buf[256];
    int t = threadIdx.x;
    int c0 = t * 40;                 // 256*40 = 10240 >= 10000
    int local[40];
    int s = 0;
    for (int i = 0; i < 40; i++) {
        int idx = c0 + i;
        int d = (idx < N_NODES) ? deg[idx] : 0;
        local[i] = d;
        s += d;
    }
    buf[t] = s;
    __syncthreads();
    for (int st = 1; st < 256; st <<= 1) {          // Hillis-Steele inclusive scan
        int v = (t >= st) ? buf[t - st] : 0;
        __syncthreads();
        buf[t] += v;
        __syncthreads();
    }
    int run = buf[t] - s;            // exclusive prefix for this chunk
    for (int i = 0; i < 40; i++) {
        int idx = c0 + i;
        if (idx < N_NODES) {
            off[idx] = run;
            cursor[idx] = run;
            run += local[i];
        }
    }
    if (t == 255) off[N_NODES] = buf[255];
}

__global__ void k_fill(const int* __restrict__ src, const int* __restrict__ dst,
                       int* __restrict__ cursor, int* __restrict__ csr) {
    int e = blockIdx.x * 256 + threadIdx.x;
    if (e < N_EDGES) {
        int p = atomicAdd(&cursor[dst[e]], 1);
        csr[p] = src[e];
    }
}

// ---------------- gather aggregation: agg[n] = sum_{e in in(n)} x[csr_src[e]] ----------------
__global__ __launch_bounds__(256) void k_gather(const float* __restrict__ x,
                                                float* __restrict__ agg,
                                                const int* __restrict__ off,
                                                const int* __restrict__ csr) {
    __shared__ int eds[256];
    int n = blockIdx.x;
    int t = threadIdx.x;
    int e0 = off[n], e1 = off[n + 1];
    float4 acc0 = {0.f, 0.f, 0.f, 0.f};
    float4 acc1 = {0.f, 0.f, 0.f, 0.f};
    for (int base = e0; base < e1; base += 256) {
        int cnt = min(256, e1 - base);
        __syncthreads();
        if (t < cnt) eds[t] = csr[base + t];
        __syncthreads();
        for (int i = 0; i < cnt; i++) {
            const float4* xr = (const float4*)(x + (size_t)eds[i] * NODE_F);
            float4 v = xr[t];
            acc0.x += v.x; acc0.y += v.y; acc0.z += v.z; acc0.w += v.w;
            if (t + 256 < 480) {
                float4 v2 = xr[t + 256];
                acc1.x += v2.x; acc1.y += v2.y; acc1.z += v2.z; acc1.w += v2.w;
            }
        }
    }
    float4* ab = (float4*)(agg + (size_t)n * NODE_F);
    ab[t] = acc0;
    if (t + 256 < 480) ab[t + 256] = acc1;
}

// ---------------- passA (MFMA): t = ((1+eps)*x + agg) @ W + b ; stats(t1) ----------------
// Per wave: one 16-row tile; A = z[16x64] (bf16), B = W[64x64] (bf16), fp32 acc.
// A-frag lane mapping: row m=lane&15, k=(lane>>4)*8+j. B-frag: k same map, col n=lane&15.
// C/D: col = lane&15, row = (lane>>4)*4 + reg  [HW-verified].
__global__ __launch_bounds__(256) void k_passA(const float* __restrict__ x,
                                               float* __restrict__ t,  // agg in, t1 out
                                               const float* __restrict__ W,
                                               const float* __restrict__ bias,
                                               const float* __restrict__ epsp, int l,
                                               float* __restrict__ ssum, float* __restrict__ ssq) {
    int tid = threadIdx.x;
    int lane = tid & 63, wid = tid >> 6;
    int m = lane & 15, kg = lane >> 4;

    // B fragments: [kstep][ntile]
    short8 bfr[2][4];
#pragma unroll
    for (int s = 0; s < 2; s++)
#pragma unroll
        for (int nt = 0; nt < 4; nt++) {
            short8 v;
#pragma unroll
            for (int j = 0; j < 8; j++)
                v[j] = (short)f2bf(W[(s * 32 + kg * 8 + j) * 64 + nt * 16 + m]);
            bfr[s][nt] = v;
        }
    float bcol[4];
#pragma unroll
    for (int nt = 0; nt < 4; nt++) bcol[nt] = bias[nt * 16 + m];
    float e1 = 1.0f + epsp[l];

    float s0a[4] = {0.f, 0.f, 0.f, 0.f}, s1a[4] = {0.f, 0.f, 0.f, 0.f};

    for (int tile = blockIdx.x * 4 + wid; tile < N_TILES; tile += gridDim.x * 4) {
        size_t row0 = (size_t)tile * 16;
        const float* xr = x + (row0 + m) * 64;
        const float* ar = t + (row0 + m) * 64;
        short8 afr[2];
#pragma unroll
        for (int s = 0; s < 2; s++) {
            float4 xa = *(const float4*)(xr + s * 32 + kg * 8);
            float4 xb = *(const float4*)(xr + s * 32 + kg * 8 + 4);
            float4 aa = *(const float4*)(ar + s * 32 + kg * 8);
            float4 ab = *(const float4*)(ar + s * 32 + kg * 8 + 4);
            short8 v;
            v[0] = (short)f2bf(fmaf(e1, xa.x, aa.x));
            v[1] = (short)f2bf(fmaf(e1, xa.y, aa.y));
            v[2] = (short)f2bf(fmaf(e1, xa.z, aa.z));
            v[3] = (short)f2bf(fmaf(e1, xa.w, aa.w));
            v[4] = (short)f2bf(fmaf(e1, xb.x, ab.x));
            v[5] = (short)f2bf(fmaf(e1, xb.y, ab.y));
            v[6] = (short)f2bf(fmaf(e1, xb.z, ab.z));
            v[7] = (short)f2bf(fmaf(e1, xb.w, ab.w));
            afr[s] = v;
        }
        f32x4 acc0 = {0,0,0,0}, acc1 = {0,0,0,0}, acc2 = {0,0,0,0}, acc3 = {0,0,0,0};
#pragma unroll
        for (int s = 0; s < 2; s++) {
            acc0 = __builtin_amdgcn_mfma_f32_16x16x32_bf16(afr[s], bfr[s][0], acc0, 0, 0, 0);
            acc1 = __builtin_amdgcn_mfma_f32_16x16x32_bf16(afr[s], bfr[s][1], acc1, 0, 0, 0);
            acc2 = __builtin_amdgcn_mfma_f32_16x16x32_bf16(afr[s], bfr[s][2], acc2, 0, 0, 0);
            acc3 = __builtin_amdgcn_mfma_f32_16x16x32_bf16(afr[s], bfr[s][3], acc3, 0, 0, 0);
        }
        float* tw = t + (row0 + kg * 4) * 64 + m;
#pragma unroll
        for (int r = 0; r < 4; r++) {
            float v0 = acc0[r] + bcol[0];
            float v1 = acc1[r] + bcol[1];
            float v2 = acc2[r] + bcol[2];
            float v3 = acc3[r] + bcol[3];
            tw[(size_t)r * 64 +  0] = v0;
            tw[(size_t)r * 64 + 16] = v1;
            tw[(size_t)r * 64 + 32] = v2;
            tw[(size_t)r * 64 + 48] = v3;
            s0a[0] += v0; s1a[0] += v0 * v0;
            s0a[1] += v1; s1a[1] += v1 * v1;
            s0a[2] += v2; s1a[2] += v2 * v2;
            s0a[3] += v3; s1a[3] += v3 * v3;
        }
    }
    __shared__ float shs0[64], shs1[64];
    if (tid < 64) { shs0[tid] = 0.f; shs1[tid] = 0.f; }
    __syncthreads();
#pragma unroll
    for (int nt = 0; nt < 4; nt++) {
        atomicAdd(&shs0[nt * 16 + m], s0a[nt]);
        atomicAdd(&shs1[nt * 16 + m], s1a[nt]);
    }
    __syncthreads();
    if (tid < 64) {
        atomicAdd(&ssum[tid], shs0[tid]);
        atomicAdd(&ssq[tid], shs1[tid]);
    }
}

// ---------------- passB (MFMA): t = relu(bn0(t)) @ W1 + b1 ; stats(t3) ----------------
__global__ __launch_bounds__(256) void k_passB(float* __restrict__ t,
                                               const float* __restrict__ W,
                                               const float* __restrict__ bias,
                                               const float* __restrict__ ssum0,
                                               const float* __restrict__ ssq0,
                                               const float* __restrict__ g0,
                                               const float* __restrict__ be0,
                                               float* __restrict__ ssum, float* __restrict__ ssq) {
    int tid = threadIdx.x;
    int lane = tid & 63, wid = tid >> 6;
    int m = lane & 15, kg = lane >> 4;

    short8 bfr[2][4];
#pragma unroll
    for (int s = 0; s < 2; s++)
#pragma unroll
        for (int nt = 0; nt < 4; nt++) {
            short8 v;
#pragma unroll
            for (int j = 0; j < 8; j++)
                v[j] = (short)f2bf(W[(s * 32 + kg * 8 + j) * 64 + nt * 16 + m]);
            bfr[s][nt] = v;
        }
    float bcol[4];
#pragma unroll
    for (int nt = 0; nt < 4; nt++) bcol[nt] = bias[nt * 16 + m];
    // BN coefficients for this lane's 16 input channels: k = s*32 + kg*8 + j
    float scv[2][8], shv[2][8];
#pragma unroll
    for (int s = 0; s < 2; s++)
#pragma unroll
        for (int j = 0; j < 8; j++)
            bn_coef(ssum0, ssq0, g0, be0, s * 32 + kg * 8 + j, scv[s][j], shv[s][j]);

    float s0a[4] = {0.f, 0.f, 0.f, 0.f}, s1a[4] = {0.f, 0.f, 0.f, 0.f};

    for (int tile = blockIdx.x * 4 + wid; tile < N_TILES; tile += gridDim.x * 4) {
        size_t row0 = (size_t)tile * 16;
        const float* tr = t + (row0 + m) * 64;
        short8 afr[2];
#pragma unroll
        for (int s = 0; s < 2; s++) {
            float4 ta = *(const float4*)(tr + s * 32 + kg * 8);
            float4 tb = *(const float4*)(tr + s * 32 + kg * 8 + 4);
            short8 v;
            v[0] = (short)f2bf(fmaxf(fmaf(ta.x, scv[s][0], shv[s][0]), 0.f));
            v[1] = (short)f2bf(fmaxf(fmaf(ta.y, scv[s][1], shv[s][1]), 0.f));
            v[2] = (short)f2bf(fmaxf(fmaf(ta.z, scv[s][2], shv[s][2]), 0.f));
            v[3] = (short)f2bf(fmaxf(fmaf(ta.w, scv[s][3], shv[s][3]), 0.f));
            v[4] = (short)f2bf(fmaxf(fmaf(tb.x, scv[s][4], shv[s][4]), 0.f));
            v[5] = (short)f2bf(fmaxf(fmaf(tb.y, scv[s][5], shv[s][5]), 0.f));
            v[6] = (short)f2bf(fmaxf(fmaf(tb.z, scv[s][6], shv[s][6]), 0.f));
            v[7] = (short)f2bf(fmaxf(fmaf(tb.w, scv[s][7], shv[s][7]), 0.f));
            afr[s] = v;
        }
        f32x4 acc0 = {0,0,0,0}, acc1 = {0,0,0,0}, acc2 = {0,0,0,0}, acc3 = {0,0,0,0};
#pragma unroll
        for (int s = 0; s < 2; s++) {
            acc0 = __builtin_amdgcn_mfma_f32_16x16x32_bf16(afr[s], bfr[s][0], acc0, 0, 0, 0);
            acc1 = __builtin_amdgcn_mfma_f32_16x16x32_bf16(afr[s], bfr[s][1], acc1, 0, 0, 0);
            acc2 = __builtin_amdgcn_mfma_f32_16x16x32_bf16(afr[s], bfr[s][2], acc2, 0, 0, 0);
            acc3 = __builtin_amdgcn_mfma_f32_16x16x32_bf16(afr[s], bfr[s][3], acc3, 0, 0, 0);
        }
        float* tw = t + (row0 + kg * 4) * 64 + m;
#pragma unroll
        for (int r = 0; r < 4; r++) {
            float v0 = acc0[r] + bcol[0];
            float v1 = acc1[r] + bcol[1];
            float v2 = acc2[r] + bcol[2];
            float v3 = acc3[r] + bcol[3];
            tw[(size_t)r * 64 +  0] = v0;
            tw[(size_t)r * 64 + 16] = v1;
            tw[(size_t)r * 64 + 32] = v2;
            tw[(size_t)r * 64 + 48] = v3;
            s0a[0] += v0; s1a[0] += v0 * v0;
            s0a[1] += v1; s1a[1] += v1 * v1;
            s0a[2] += v2; s1a[2] += v2 * v2;
            s0a[3] += v3; s1a[3] += v3 * v3;
        }
    }
    __shared__ float shs0[64], shs1[64];
    if (tid < 64) { shs0[tid] = 0.f; shs1[tid] = 0.f; }
    __syncthreads();
#pragma unroll
    for (int nt = 0; nt < 4; nt++) {
        atomicAdd(&shs0[nt * 16 + m], s0a[nt]);
        atomicAdd(&shs1[nt * 16 + m], s1a[nt]);
    }
    __syncthreads();
    if (tid < 64) {
        atomicAdd(&ssum[tid], shs0[tid]);
        atomicAdd(&ssq[tid], shs1[tid]);
    }
}

// ---------------- statsC: stats of u = relu(bn_a(t3)), read-only ----------------
__global__ __launch_bounds__(256) void k_statsC(const float* __restrict__ t,
                                                const float* __restrict__ ssum1,
                                                const float* __restrict__ ssq1,
                                                const float* __restrict__ ga,
                                                const float* __restrict__ ba,
                                                float* __restrict__ ssum2,
                                                float* __restrict__ ssq2) {
    __shared__ float shs0[64], shs1[64];
    int tid = threadIdx.x;
    if (tid < 64) { shs0[tid] = 0.f; shs1[tid] = 0.f; }
    __syncthreads();
    int q = tid & 15;
    float sc[4], sh[4];
#pragma unroll
    for (int u = 0; u < 4; u++) bn_coef(ssum1, ssq1, ga, ba, q * 4 + u, sc[u], sh[u]);
    float s0[4] = {0, 0, 0, 0}, s1[4] = {0, 0, 0, 0};
    const float4* t4 = (const float4*)t;
    const int total4 = ELEMS / 4;
    int stride = gridDim.x * 256;
    for (int i = blockIdx.x * 256 + tid; i < total4; i += stride) {
        float4 v = t4[i];
        float e;
        e = fmaxf(fmaf(v.x, sc[0], sh[0]), 0.f); s0[0] += e; s1[0] += e * e;
        e = fmaxf(fmaf(v.y, sc[1], sh[1]), 0.f); s0[1] += e; s1[1] += e * e;
        e = fmaxf(fmaf(v.z, sc[2], sh[2]), 0.f); s0[2] += e; s1[2] += e * e;
        e = fmaxf(fmaf(v.w, sc[3], sh[3]), 0.f); s0[3] += e; s1[3] += e * e;
    }
#pragma unroll
    for (int u = 0; u < 4; u++) {
        atomicAdd(&shs0[q * 4 + u], s0[u]);
        atomicAdd(&shs1[q * 4 + u], s1[u]);
    }
    __syncthreads();
    if (tid < 64) {
        atomicAdd(&ssum2[tid], shs0[tid]);
        atomicAdd(&ssq2[tid], shs1[tid]);
    }
}

// ---------------- passD: x = relu(bn_o(relu(bn_a(t3)))) in place + pooled ----------------
__global__ __launch_bounds__(256) void k_passD(float* __restrict__ t,
                                               const float* __restrict__ ssum1,
                                               const float* __restrict__ ssq1,
                                               const float* __restrict__ ga,
                                               const float* __restrict__ ba,
                                               const float* __restrict__ ssum2,
                                               const float* __restrict__ ssq2,
                                               const float* __restrict__ go,
                                               const float* __restrict__ bo,
                                               float* __restrict__ pooled) {
    int tid = threadIdx.x;
    int q = tid & 15;                 // same channel set for tid and tid+256
    float sc1[4], sh1[4], sc2[4], sh2[4];
#pragma unroll
    for (int u = 0; u < 4; u++) {
        bn_coef(ssum1, ssq1, ga, ba, q * 4 + u, sc1[u], sh1[u]);
        bn_coef(ssum2, ssq2, go, bo, q * 4 + u, sc2[u], sh2[u]);
    }
    float4 P0 = {0, 0, 0, 0}, P1 = {0, 0, 0, 0};
    bool two = (tid < 480 - 256);
    for (int n = blockIdx.x; n < N_NODES; n += gridDim.x) {
        float4* tb = (float4*)(t + (size_t)n * NODE_F);
        float4 v = tb[tid];
        v.x = fmaxf(fmaf(fmaxf(fmaf(v.x, sc1[0], sh1[0]), 0.f), sc2[0], sh2[0]), 0.f);
        v.y = fmaxf(fmaf(fmaxf(fmaf(v.y, sc1[1], sh1[1]), 0.f), sc2[1], sh2[1]), 0.f);
        v.z = fmaxf(fmaf(fmaxf(fmaf(v.z, sc1[2], sh1[2]), 0.f), sc2[2], sh2[2]), 0.f);
        v.w = fmaxf(fmaf(fmaxf(fmaf(v.w, sc1[3], sh1[3]), 0.f), sc2[3], sh2[3]), 0.f);
        tb[tid] = v;
        P0.x += v.x; P0.y += v.y; P0.z += v.z; P0.w += v.w;
        if (two) {
            float4 v2 = tb[tid + 256];
            v2.x = fmaxf(fmaf(fmaxf(fmaf(v2.x, sc1[0], sh1[0]), 0.f), sc2[0], sh2[0]), 0.f);
            v2.y = fmaxf(fmaf(fmaxf(fmaf(v2.y, sc1[1], sh1[1]), 0.f), sc2[1], sh2[1]), 0.f);
            v2.z = fmaxf(fmaf(fmaxf(fmaf(v2.z, sc1[2], sh1[2]), 0.f), sc2[2], sh2[2]), 0.f);
            v2.w = fmaxf(fmaf(fmaxf(fmaf(v2.w, sc1[3], sh1[3]), 0.f), sc2[3], sh2[3]), 0.f);
            tb[tid + 256] = v2;
            P1.x += v2.x; P1.y += v2.y; P1.z += v2.z; P1.w += v2.w;
        }
    }
    float* pb0 = pooled + tid * 4;
    atomicAdd(pb0 + 0, P0.x); atomicAdd(pb0 + 1, P0.y);
    atomicAdd(pb0 + 2, P0.z); atomicAdd(pb0 + 3, P0.w);
    if (two) {
        float* pb1 = pooled + (tid + 256) * 4;
        atomicAdd(pb1 + 0, P1.x); atomicAdd(pb1 + 1, P1.y);
        atomicAdd(pb1 + 2, P1.z); atomicAdd(pb1 + 3, P1.w);
    }
}

// ---------------- final readout: score + fc -> out[2] ----------------
__global__ void k_final(const float* __restrict__ pooled,   // [3][1920]
                        const float* __restrict__ Wp,       // [3][64][10]
                        const float* __restrict__ bp,       // [3][10]
                        const float* __restrict__ Wfc,      // [15][10]
                        const float* __restrict__ bfc, float* __restrict__ out) {
    __shared__ float oa[2];
    int t = threadIdx.x;
    if (t < 2) oa[t] = 0.f;
    __syncthreads();
    if (t < 300) {
        int a = t / 150, rem = t % 150, c = rem / 10, hh = rem % 10;
        int ac = a * 15 + c;
        float sc_sum = 0.f;
        for (int i = 0; i < 3; i++) {
            float s = bp[i * 10 + hh];
            const float* pp = pooled + i * NODE_F + ac * 64;
            const float* wp = Wp + i * 640 + hh;
            for (int d = 0; d < 64; d++) s += pp[d] * wp[d * 10];
            sc_sum += s;
        }
        atomicAdd(&oa[a], sc_sum * Wfc[c * 10 + hh]);
    }
    __syncthreads();
    if (t < 2) out[t] = oa[t] + bfc[0];
}

extern "C" void kernel_launch(void* const* d_in, const int* in_sizes, int n_in,
                              void* d_out, int out_size, void* d_ws, size_t ws_size,
                              hipStream_t stream) {
    const float* h   = (const float*)d_in[0];
    const float* eps = (const float*)d_in[1];
    const float* W0  = (const float*)d_in[2];
    const float* b0  = (const float*)d_in[3];
    const float* g0  = (const float*)d_in[4];
    const float* be0 = (const float*)d_in[5];
    const float* W1  = (const float*)d_in[6];
    const float* b1  = (const float*)d_in[7];
    const float* ga  = (const float*)d_in[8];
    const float* ba  = (const float*)d_in[9];
    const float* go  = (const float*)d_in[10];
    const float* bo  = (const float*)d_in[11];
    const float* Wp  = (const float*)d_in[12];
    const float* bp  = (const float*)d_in[13];
    const float* Wfc = (const float*)d_in[14];
    const float* bfc = (const float*)d_in[15];
    const int*   src = (const int*)d_in[16];
    const int*   dst = (const int*)d_in[17];
    float* out = (float*)d_out;

    float* bufA = (float*)d_ws;
    float* bufB = bufA + ELEMS;
    float* small = bufB + ELEMS;
    float* bn = small;                   // 6 BN instances x [sum64|sq64] (+pad to 256)
    float* pooled = small + 6 * 256;     // [3][1920]
    int* ideg   = (int*)(pooled + 3 * NODE_F);   // [10000]
    int* ioff   = ideg + N_NODES;                // [10001]
    int* icur   = ioff + N_NODES + 1;            // [10000]
    int* icsr   = icur + N_NODES;                // [80000]

    // zero: bn stats + pooled + deg histogram (one contiguous region)
    hipMemsetAsync(small, 0,
                   (6 * 256 + 3 * NODE_F) * sizeof(float) + N_NODES * sizeof(int), stream);

    // CSR build (once; reused by both layers)
    k_deg<<<(N_EDGES + 255) / 256, 256, 0, stream>>>(dst, ideg);
    k_scan<<<1, 256, 0, stream>>>(ideg, ioff, icur);
    k_fill<<<(N_EDGES + 255) / 256, 256, 0, stream>>>(src, dst, icur, icsr);

    k_transpose<<<dim3(157, 30), 256, 0, stream>>>(h, bufA, pooled);

    float* cur = bufA;
    float* oth = bufB;
    for (int l = 0; l < 2; l++) {
        float* s0s = bn + l * 3 * 256;
        float* s1s = s0s + 256;
        float* s2s = s1s + 256;
        k_gather<<<N_NODES, 256, 0, stream>>>(cur, oth, ioff, icsr);
        k_passA<<<2048, 256, 0, stream>>>(cur, oth, W0 + l * 4096, b0 + l * 64, eps, l,
                                          s0s, s0s + 64);
        k_passB<<<2048, 256, 0, stream>>>(oth, W1 + l * 4096, b1 + l * 64,
                                          s0s, s0s + 64, g0 + l * 64, be0 + l * 64,
                                          s1s, s1s + 64);
        k_statsC<<<1024, 256, 0, stream>>>(oth, s1s, s1s + 64, ga + l * 64, ba + l * 64,
                                           s2s, s2s + 64);
        k_passD<<<640, 256, 0, stream>>>(oth, s1s, s1s + 64, ga + l * 64, ba + l * 64,
                                         s2s, s2s + 64, go + l * 64, bo + l * 64,
                                         pooled + (l + 1) * NODE_F);
        float* tmp = cur; cur = oth; oth = tmp;
    }
    k_final<<<1, 320, 0, stream>>>(pooled, Wp, bp, Wfc, bfc, out);
}